// Round 8
// baseline (1409.069 us; speedup 1.0000x reference)
//
#include <hip/hip_runtime.h>
#include <hip/hip_bf16.h>
#include <math.h>

#define NN 8192
#define KK 1000
#define SS 8
#define DD 1024
#define RR (KK * SS)   // 8000 memory rows
#define RRP 8192       // padded to 32 * 256

typedef __bf16 bf16x8 __attribute__((ext_vector_type(8)));
typedef float f32x4 __attribute__((ext_vector_type(4)));
typedef unsigned short ushort_t;
typedef ushort_t ushort8 __attribute__((ext_vector_type(8)));

static __device__ __forceinline__ ushort_t f2bf(float f) {
  unsigned u = __float_as_uint(f);
  unsigned r = (u + 0x7FFFu + ((u >> 16) & 1u)) >> 16;  // round-nearest-even
  return (ushort_t)r;
}

// direct global->LDS DMA, 16 B per lane; LDS dest = wave-uniform base + lane*16
#define GLD16(gsrc, ldst)                                                     \
  __builtin_amdgcn_global_load_lds(                                           \
      (const __attribute__((address_space(1))) unsigned int*)(gsrc),          \
      (__attribute__((address_space(3))) unsigned int*)(ldst), 16, 0, 0)

#define SBAR() asm volatile("s_barrier" ::: "memory")
#define WAITVM(n) asm volatile("s_waitcnt vmcnt(" #n ")" ::: "memory")

// ---------------------------------------------------------------------------
// Kernel A: per-sample softmax stats -> packed candidate record.
// ---------------------------------------------------------------------------
__global__ __launch_bounds__(256) void stats_kernel(
    const float* __restrict__ tl, int2* __restrict__ cand) {
  __shared__ float sv[KK];
  __shared__ float redv[256];
  __shared__ int   redi[256];
  const int n = blockIdx.x;
  const int t = threadIdx.x;
  const float* row = tl + (size_t)n * KK;
  for (int j = t; j < KK; j += 256) sv[j] = row[j];
  __syncthreads();

  float bv = -INFINITY; int bi = KK;
  for (int j = t; j < KK; j += 256) { float v = sv[j]; if (v > bv) { bv = v; bi = j; } }
  redv[t] = bv; redi[t] = bi;
  __syncthreads();
  for (int off = 128; off > 0; off >>= 1) {
    if (t < off) {
      float ov = redv[t + off]; int oi = redi[t + off];
      if (ov > redv[t] || (ov == redv[t] && oi < redi[t])) { redv[t] = ov; redi[t] = oi; }
    }
    __syncthreads();
  }
  const float m = redv[0];
  const int lab = redi[0];
  __syncthreads();

  float z = 0.f;
  for (int j = t; j < KK; j += 256) z += expf(sv[j] - m);
  redv[t] = z;
  __syncthreads();
  for (int off = 128; off > 0; off >>= 1) {
    if (t < off) redv[t] += redv[t + off];
    __syncthreads();
  }
  const float Z = redv[0];
  __syncthreads();

  float h = 0.f;
  for (int j = t; j < KK; j += 256) {
    float p = expf(sv[j] - m) / Z;
    h -= p * logf(p + 1e-6f);
  }
  redv[t] = h;
  __syncthreads();
  for (int off = 128; off > 0; off >>= 1) {
    if (t < off) redv[t] += redv[t + off];
    __syncthreads();
  }
  if (t == 0) {
    const float H = redv[0];
    const float plab = 1.0f / Z;
    const bool c = (plab > 0.03f) && (H > 0.2f) && (H < 0.5f);
    cand[n] = make_int2(c ? lab : -1, __float_as_int(H));
  }
}

// ---------------------------------------------------------------------------
// Kernel B: per-class sequential eviction, wave-parallel scan.
// ---------------------------------------------------------------------------
__global__ __launch_bounds__(256) void select_kernel(
    const int2* __restrict__ cand, const float* __restrict__ ment,
    int* __restrict__ sel) {
  const int w = threadIdx.x >> 6;
  const int l = threadIdx.x & 63;
  const int k = blockIdx.x * 4 + w;
  if (k >= KK) return;

  float ent[SS]; int idx[SS];
  #pragma unroll
  for (int s = 0; s < SS; ++s) { ent[s] = ment[k * SS + s]; idx[s] = -1; }

  for (int base = 0; base < NN; base += 64) {
    const int2 c = cand[base + l];
    unsigned long long msk = __ballot(c.x == k);
    while (msk) {
      const int src = __ffsll((long long)msk) - 1;
      msk &= msk - 1;
      const float H = __shfl(__int_as_float(c.y), src);
      float mx = ent[0]; int mi = 0;
      #pragma unroll
      for (int s = 1; s < SS; ++s) if (ent[s] > mx) { mx = ent[s]; mi = s; }
      if (H < mx) { ent[mi] = H; idx[mi] = base + src; }
    }
  }
  if (l == 0) {
    #pragma unroll
    for (int s = 0; s < SS; ++s) sel[k * SS + s] = idx[s];
  }
}

// ---------------------------------------------------------------------------
// Kernel B2: fused convert+gather.
// r < NN:  xb[r]  = bf16(x[r])
// r >= NN: Bb[r-NN] = bf16(final memory row r-NN)  (sel>=0 -> x row, pad->0)
// ---------------------------------------------------------------------------
__global__ __launch_bounds__(128) void convgather_kernel(
    const float* __restrict__ x, const float* __restrict__ mem,
    const int* __restrict__ sel, ushort_t* __restrict__ xb,
    ushort_t* __restrict__ Bb) {
  const int r = blockIdx.x;
  const int t = threadIdx.x;
  const float* src;
  ushort_t* dst;
  if (r < NN) {
    src = x + (size_t)r * DD;
    dst = xb + (size_t)r * DD;
  } else {
    const int rr = r - NN;
    dst = Bb + (size_t)rr * DD;
    if (rr >= RR) {
      *(ushort8*)(dst + t * 8) = (ushort8)0;
      return;
    }
    const int sl = sel[rr];
    src = (sl >= 0) ? (x + (size_t)sl * DD) : (mem + (size_t)rr * DD);
  }
  const float4 a = *(const float4*)(src + t * 8);
  const float4 b = *(const float4*)(src + t * 8 + 4);
  ushort8 o;
  o[0] = f2bf(a.x); o[1] = f2bf(a.y); o[2] = f2bf(a.z); o[3] = f2bf(a.w);
  o[4] = f2bf(b.x); o[5] = f2bf(b.y); o[6] = f2bf(b.z); o[7] = f2bf(b.w);
  *(ushort8*)(dst + t * 8) = o;
}

// ---------------------------------------------------------------------------
// Kernel C: bf16 MFMA GEMM + exp-sum epilogue, double-buffered, 2 blocks/CU.
// 256x256 tile, BK=32, 8 waves (2M x 4N), 512 threads, 2 LDS K-tile buffers
// (64 KB -> 2 blocks/CU, 4 waves/SIMD: barrier/waitcnt stalls of one block
// covered by the other).  Depth-1 pipeline: STAGE(T+1) issued at TOP of iter
// T (~2500 cyc before the end-of-iter WAITVM(0) -> L2 latency fully hidden;
// unlike m97's stage-after-compute drain).
// Ledger: buf[(T+1)&1]'s last reads were in iter T-1, before that iter's
// barrier; STAGE writes are issued in iter T, after it. WAITVM(0)+SBAR at
// iter end -> tile T+1 resident for all waves.
// Chunk-XOR swizzle (verified 0 bank conflicts r5-r7):
//   LDS[row][c] = G[row][c ^ ((row>>1)&3)] (16B chunks, 64 B rows),
//   staged by permuting the per-lane GLOBAL source, read with the same XOR.
// ---------------------------------------------------------------------------
#define BKT 32
#define NT (DD / BKT)  // 32 K-tiles

__global__ __launch_bounds__(512, 4) void logits_kernel(
    const ushort_t* __restrict__ xb, const ushort_t* __restrict__ Bb,
    float* __restrict__ out) {
  // 2 buffers x (A 8192 + B 8192 ushorts) = 32768 ushorts = 64 KB
  __shared__ ushort_t lds[2 * 16384];
  const int t = threadIdx.x;
  const int w = t >> 6;    // wave 0..7
  const int l = t & 63;
  const int wm = w >> 2;   // 0..1: M-half (128 rows)
  const int wn = w & 3;    // 0..3: N-quarter (64 cols)
  const int n0 = blockIdx.x * 256;
  const int r0 = blockIdx.y * 256;

  // ---- staging constants ----
  const int srow = w * 16 + (l >> 2);
  const int schunkh = (((l & 3) ^ ((l >> 3) & 3)) << 3);  // halves
  const ushort_t* gA0 = xb + (size_t)(n0 + srow) * DD + schunkh;
  const ushort_t* gA1 = xb + (size_t)(n0 + srow + 128) * DD + schunkh;
  const ushort_t* gB0 = Bb + (size_t)(r0 + srow) * DD + schunkh;
  const ushort_t* gB1 = Bb + (size_t)(r0 + srow + 128) * DD + schunkh;

#define STAGE_A(T, p) do {                                                    \
    GLD16(gA0 + (size_t)(T) * BKT, lds + (p) * 16384 + w * 512);              \
    GLD16(gA1 + (size_t)(T) * BKT, lds + (p) * 16384 + 4096 + w * 512);       \
  } while (0)
#define STAGE_B(T, p) do {                                                    \
    GLD16(gB0 + (size_t)(T) * BKT, lds + (p) * 16384 + 8192 + w * 512);       \
    GLD16(gB1 + (size_t)(T) * BKT, lds + (p) * 16384 + 12288 + w * 512);      \
  } while (0)

  // ---- read-side constants (ushort units) ----
  const int lr = l & 15;
  const int ch = l >> 4;                       // 16B k-chunk 0..3
  const int swz = ((ch ^ ((lr >> 1) & 3)) << 3);
  const int Aoff = (wm * 128 + lr) * 32 + swz;          // + mi*512
  const int Boff = 8192 + (wn * 64 + lr) * 32 + swz;    // + ni*512

  f32x4 acc[8][4];
  #pragma unroll
  for (int mi = 0; mi < 8; ++mi)
    #pragma unroll
    for (int ni = 0; ni < 4; ++ni) acc[mi][ni] = (f32x4){0.f, 0.f, 0.f, 0.f};

  // ---- prologue: stage tile 0 ----
  STAGE_A(0, 0); STAGE_B(0, 0);
  WAITVM(0);
  SBAR();

  #pragma unroll 2
  for (int T = 0; T < NT; ++T) {
    const int p = T & 1;
    const ushort_t* buf = lds + p * 16384;
    bf16x8 af0[4], af1[4], bfr[4];

    // issue next tile's DMA early (hidden under this tile's compute)
    if (T + 1 < NT) { STAGE_A(T + 1, (T + 1) & 1); STAGE_B(T + 1, (T + 1) & 1); }

    // frag reads for the whole K-tile (compiler pipelines with MFMA below)
    #pragma unroll
    for (int mi = 0; mi < 4; ++mi)
      af0[mi] = *(const bf16x8*)(buf + Aoff + mi * 512);
    #pragma unroll
    for (int ni = 0; ni < 4; ++ni)
      bfr[ni] = *(const bf16x8*)(buf + Boff + ni * 512);
    #pragma unroll
    for (int mi = 0; mi < 4; ++mi)
      af1[mi] = *(const bf16x8*)(buf + Aoff + 2048 + mi * 512);

    __builtin_amdgcn_s_setprio(1);
    #pragma unroll
    for (int mi = 0; mi < 4; ++mi)
      #pragma unroll
      for (int ni = 0; ni < 4; ++ni)
        acc[mi][ni] = __builtin_amdgcn_mfma_f32_16x16x32_bf16(
            af0[mi], bfr[ni], acc[mi][ni], 0, 0, 0);
    #pragma unroll
    for (int mi = 0; mi < 4; ++mi)
      #pragma unroll
      for (int ni = 0; ni < 4; ++ni)
        acc[mi + 4][ni] = __builtin_amdgcn_mfma_f32_16x16x32_bf16(
            af1[mi], bfr[ni], acc[mi + 4][ni], 0, 0, 0);
    __builtin_amdgcn_s_setprio(0);

    // tile boundary: next tile's DMA (issued ~full tile ago) must be done
    WAITVM(0);
    SBAR();
  }

  // ---- epilogue: exp-sum over 8 slot-columns per class ----
  const int rbase = n0 + wm * 128 + ((l >> 4) * 4);
  #pragma unroll
  for (int mi = 0; mi < 8; ++mi) {
    #pragma unroll
    for (int ni = 0; ni < 4; ++ni) {
      const int colbase = r0 + wn * 64 + ni * 16 + (l & 15);
      const int cls = colbase >> 3;
      #pragma unroll
      for (int rg = 0; rg < 4; ++rg) {
        float e = __expf(acc[mi][ni][rg] - 1.0f);
        e += __shfl_xor(e, 1);
        e += __shfl_xor(e, 2);
        e += __shfl_xor(e, 4);
        if ((l & 7) == 0 && cls < KK) {
          out[(size_t)(rbase + mi * 16 + rg) * KK + cls] = -fminf(e, 3.0e38f);
        }
      }
    }
  }
}

extern "C" void kernel_launch(void* const* d_in, const int* in_sizes, int n_in,
                              void* d_out, int out_size, void* d_ws, size_t ws_size,
                              hipStream_t stream) {
  const float* x    = (const float*)d_in[0];
  const float* tl   = (const float*)d_in[1];
  const float* mem  = (const float*)d_in[2];
  const float* ment = (const float*)d_in[3];
  float* out = (float*)d_out;

  char* ws = (char*)d_ws;
  int2*     cand = (int2*)ws;                      // 64 KB
  int*      sel  = (int*)(ws + NN * 8);            // 32 KB
  ushort_t* Bb   = (ushort_t*)(ws + (1 << 20));                        // RRP*DD*2 = 16.78 MB
  ushort_t* xb   = (ushort_t*)(ws + (1 << 20) + (size_t)RRP * DD * 2); // NN*DD*2 = 16.78 MB

  hipLaunchKernelGGL(stats_kernel, dim3(NN), dim3(256), 0, stream, tl, cand);
  hipLaunchKernelGGL(select_kernel, dim3(250), dim3(256), 0, stream, cand, ment, sel);
  hipLaunchKernelGGL(convgather_kernel, dim3(NN + RRP), dim3(128), 0, stream,
                     x, mem, sel, xb, Bb);
  hipLaunchKernelGGL(logits_kernel, dim3(32, 32), dim3(512), 0, stream, xb, Bb, out);
}

// Round 9
// 241.509 us; speedup vs baseline: 5.8344x; 5.8344x over previous
//
#include <hip/hip_runtime.h>
#include <hip/hip_bf16.h>
#include <math.h>

#define NN 8192
#define KK 1000
#define SS 8
#define DD 1024
#define RR (KK * SS)   // 8000 memory rows
#define RRP 8192       // padded to 32 * 256

typedef __bf16 bf16x8 __attribute__((ext_vector_type(8)));
typedef float f32x4 __attribute__((ext_vector_type(4)));
typedef unsigned short ushort_t;
typedef ushort_t ushort8 __attribute__((ext_vector_type(8)));

static __device__ __forceinline__ ushort_t f2bf(float f) {
  unsigned u = __float_as_uint(f);
  unsigned r = (u + 0x7FFFu + ((u >> 16) & 1u)) >> 16;  // round-nearest-even
  return (ushort_t)r;
}

// direct global->LDS DMA, 16 B per lane; LDS dest = wave-uniform base + lane*16
#define GLD16(gsrc, ldst)                                                     \
  __builtin_amdgcn_global_load_lds(                                           \
      (const __attribute__((address_space(1))) unsigned int*)(gsrc),          \
      (__attribute__((address_space(3))) unsigned int*)(ldst), 16, 0, 0)

#define SBAR() asm volatile("s_barrier" ::: "memory")
#define WAITVM(n) asm volatile("s_waitcnt vmcnt(" #n ")" ::: "memory")

// ---------------------------------------------------------------------------
// Kernel A: per-sample softmax stats -> packed candidate record.
// ---------------------------------------------------------------------------
__global__ __launch_bounds__(256) void stats_kernel(
    const float* __restrict__ tl, int2* __restrict__ cand) {
  __shared__ float sv[KK];
  __shared__ float redv[256];
  __shared__ int   redi[256];
  const int n = blockIdx.x;
  const int t = threadIdx.x;
  const float* row = tl + (size_t)n * KK;
  for (int j = t; j < KK; j += 256) sv[j] = row[j];
  __syncthreads();

  float bv = -INFINITY; int bi = KK;
  for (int j = t; j < KK; j += 256) { float v = sv[j]; if (v > bv) { bv = v; bi = j; } }
  redv[t] = bv; redi[t] = bi;
  __syncthreads();
  for (int off = 128; off > 0; off >>= 1) {
    if (t < off) {
      float ov = redv[t + off]; int oi = redi[t + off];
      if (ov > redv[t] || (ov == redv[t] && oi < redi[t])) { redv[t] = ov; redi[t] = oi; }
    }
    __syncthreads();
  }
  const float m = redv[0];
  const int lab = redi[0];
  __syncthreads();

  float z = 0.f;
  for (int j = t; j < KK; j += 256) z += expf(sv[j] - m);
  redv[t] = z;
  __syncthreads();
  for (int off = 128; off > 0; off >>= 1) {
    if (t < off) redv[t] += redv[t + off];
    __syncthreads();
  }
  const float Z = redv[0];
  __syncthreads();

  float h = 0.f;
  for (int j = t; j < KK; j += 256) {
    float p = expf(sv[j] - m) / Z;
    h -= p * logf(p + 1e-6f);
  }
  redv[t] = h;
  __syncthreads();
  for (int off = 128; off > 0; off >>= 1) {
    if (t < off) redv[t] += redv[t + off];
    __syncthreads();
  }
  if (t == 0) {
    const float H = redv[0];
    const float plab = 1.0f / Z;
    const bool c = (plab > 0.03f) && (H > 0.2f) && (H < 0.5f);
    cand[n] = make_int2(c ? lab : -1, __float_as_int(H));
  }
}

// ---------------------------------------------------------------------------
// Kernel B: per-class sequential eviction, wave-parallel scan.
// ---------------------------------------------------------------------------
__global__ __launch_bounds__(256) void select_kernel(
    const int2* __restrict__ cand, const float* __restrict__ ment,
    int* __restrict__ sel) {
  const int w = threadIdx.x >> 6;
  const int l = threadIdx.x & 63;
  const int k = blockIdx.x * 4 + w;
  if (k >= KK) return;

  float ent[SS]; int idx[SS];
  #pragma unroll
  for (int s = 0; s < SS; ++s) { ent[s] = ment[k * SS + s]; idx[s] = -1; }

  for (int base = 0; base < NN; base += 64) {
    const int2 c = cand[base + l];
    unsigned long long msk = __ballot(c.x == k);
    while (msk) {
      const int src = __ffsll((long long)msk) - 1;
      msk &= msk - 1;
      const float H = __shfl(__int_as_float(c.y), src);
      float mx = ent[0]; int mi = 0;
      #pragma unroll
      for (int s = 1; s < SS; ++s) if (ent[s] > mx) { mx = ent[s]; mi = s; }
      if (H < mx) { ent[mi] = H; idx[mi] = base + src; }
    }
  }
  if (l == 0) {
    #pragma unroll
    for (int s = 0; s < SS; ++s) sel[k * SS + s] = idx[s];
  }
}

// ---------------------------------------------------------------------------
// Kernel B2: fused convert+gather.
// r < NN:  xb[r]  = bf16(x[r])
// r >= NN: Bb[r-NN] = bf16(final memory row r-NN)  (sel>=0 -> x row, pad->0)
// ---------------------------------------------------------------------------
__global__ __launch_bounds__(128) void convgather_kernel(
    const float* __restrict__ x, const float* __restrict__ mem,
    const int* __restrict__ sel, ushort_t* __restrict__ xb,
    ushort_t* __restrict__ Bb) {
  const int r = blockIdx.x;
  const int t = threadIdx.x;
  const float* src;
  ushort_t* dst;
  if (r < NN) {
    src = x + (size_t)r * DD;
    dst = xb + (size_t)r * DD;
  } else {
    const int rr = r - NN;
    dst = Bb + (size_t)rr * DD;
    if (rr >= RR) {
      *(ushort8*)(dst + t * 8) = (ushort8)0;
      return;
    }
    const int sl = sel[rr];
    src = (sl >= 0) ? (x + (size_t)sl * DD) : (mem + (size_t)rr * DD);
  }
  const float4 a = *(const float4*)(src + t * 8);
  const float4 b = *(const float4*)(src + t * 8 + 4);
  ushort8 o;
  o[0] = f2bf(a.x); o[1] = f2bf(a.y); o[2] = f2bf(a.z); o[3] = f2bf(a.w);
  o[4] = f2bf(b.x); o[5] = f2bf(b.y); o[6] = f2bf(b.z); o[7] = f2bf(b.w);
  *(ushort8*)(dst + t * 8) = o;
}

// ---------------------------------------------------------------------------
// Kernel C: bf16 MFMA GEMM + exp-sum epilogue, double-buffered, 2 blocks/CU.
// 256x256 tile, BK=32, 8 waves (2M x 4N), 512 threads, 2 LDS K-tile buffers
// (64 KB -> 2 blocks/CU by LDS).  __launch_bounds__(512, 2): r8's (512,4)
// capped the unified VGPR/AGPR budget at 128/wave -> acc[8][4] spilled to
// scratch (VGPR_Count 64, WRITE_SIZE 4 GB, 10x regression). With min=2 the
// compiler allocates 128 regs (r7-proven, no spill) and the HW still
// co-schedules 2 blocks/CU (128 VGPR allows 4 waves/SIMD; LDS 2x64<=160KB).
// Depth-1 pipeline: STAGE(T+1) issued at TOP of iter T (~2500 cyc before the
// end-of-iter WAITVM(0) -> L2 latency fully hidden).
// Ledger: buf[(T+1)&1]'s last reads were in iter T-1, before that iter's
// barrier; STAGE writes are issued in iter T, after it. WAITVM(0)+SBAR at
// iter end -> tile T+1 resident for all waves.
// Chunk-XOR swizzle (verified 0 bank conflicts r5-r8):
//   LDS[row][c] = G[row][c ^ ((row>>1)&3)] (16B chunks, 64 B rows),
//   staged by permuting the per-lane GLOBAL source, read with the same XOR.
// ---------------------------------------------------------------------------
#define BKT 32
#define NT (DD / BKT)  // 32 K-tiles

__global__ __launch_bounds__(512, 2) void logits_kernel(
    const ushort_t* __restrict__ xb, const ushort_t* __restrict__ Bb,
    float* __restrict__ out) {
  // 2 buffers x (A 8192 + B 8192 ushorts) = 32768 ushorts = 64 KB
  __shared__ ushort_t lds[2 * 16384];
  const int t = threadIdx.x;
  const int w = t >> 6;    // wave 0..7
  const int l = t & 63;
  const int wm = w >> 2;   // 0..1: M-half (128 rows)
  const int wn = w & 3;    // 0..3: N-quarter (64 cols)
  const int n0 = blockIdx.x * 256;
  const int r0 = blockIdx.y * 256;

  // ---- staging constants ----
  const int srow = w * 16 + (l >> 2);
  const int schunkh = (((l & 3) ^ ((l >> 3) & 3)) << 3);  // halves
  const ushort_t* gA0 = xb + (size_t)(n0 + srow) * DD + schunkh;
  const ushort_t* gA1 = xb + (size_t)(n0 + srow + 128) * DD + schunkh;
  const ushort_t* gB0 = Bb + (size_t)(r0 + srow) * DD + schunkh;
  const ushort_t* gB1 = Bb + (size_t)(r0 + srow + 128) * DD + schunkh;

#define STAGE_A(T, p) do {                                                    \
    GLD16(gA0 + (size_t)(T) * BKT, lds + (p) * 16384 + w * 512);              \
    GLD16(gA1 + (size_t)(T) * BKT, lds + (p) * 16384 + 4096 + w * 512);       \
  } while (0)
#define STAGE_B(T, p) do {                                                    \
    GLD16(gB0 + (size_t)(T) * BKT, lds + (p) * 16384 + 8192 + w * 512);       \
    GLD16(gB1 + (size_t)(T) * BKT, lds + (p) * 16384 + 12288 + w * 512);      \
  } while (0)

  // ---- read-side constants (ushort units) ----
  const int lr = l & 15;
  const int ch = l >> 4;                       // 16B k-chunk 0..3
  const int swz = ((ch ^ ((lr >> 1) & 3)) << 3);
  const int Aoff = (wm * 128 + lr) * 32 + swz;          // + mi*512
  const int Boff = 8192 + (wn * 64 + lr) * 32 + swz;    // + ni*512

  f32x4 acc[8][4];
  #pragma unroll
  for (int mi = 0; mi < 8; ++mi)
    #pragma unroll
    for (int ni = 0; ni < 4; ++ni) acc[mi][ni] = (f32x4){0.f, 0.f, 0.f, 0.f};

  // ---- prologue: stage tile 0 ----
  STAGE_A(0, 0); STAGE_B(0, 0);
  WAITVM(0);
  SBAR();

  #pragma unroll 2
  for (int T = 0; T < NT; ++T) {
    const int p = T & 1;
    const ushort_t* buf = lds + p * 16384;
    bf16x8 af0[4], af1[4], bfr[4];

    // issue next tile's DMA early (hidden under this tile's compute)
    if (T + 1 < NT) { STAGE_A(T + 1, (T + 1) & 1); STAGE_B(T + 1, (T + 1) & 1); }

    // frag reads for the whole K-tile (compiler pipelines with MFMA below)
    #pragma unroll
    for (int mi = 0; mi < 4; ++mi)
      af0[mi] = *(const bf16x8*)(buf + Aoff + mi * 512);
    #pragma unroll
    for (int ni = 0; ni < 4; ++ni)
      bfr[ni] = *(const bf16x8*)(buf + Boff + ni * 512);
    #pragma unroll
    for (int mi = 0; mi < 4; ++mi)
      af1[mi] = *(const bf16x8*)(buf + Aoff + 2048 + mi * 512);

    __builtin_amdgcn_s_setprio(1);
    #pragma unroll
    for (int mi = 0; mi < 4; ++mi)
      #pragma unroll
      for (int ni = 0; ni < 4; ++ni)
        acc[mi][ni] = __builtin_amdgcn_mfma_f32_16x16x32_bf16(
            af0[mi], bfr[ni], acc[mi][ni], 0, 0, 0);
    #pragma unroll
    for (int mi = 0; mi < 4; ++mi)
      #pragma unroll
      for (int ni = 0; ni < 4; ++ni)
        acc[mi + 4][ni] = __builtin_amdgcn_mfma_f32_16x16x32_bf16(
            af1[mi], bfr[ni], acc[mi + 4][ni], 0, 0, 0);
    __builtin_amdgcn_s_setprio(0);

    // tile boundary: next tile's DMA (issued ~full tile ago) must be done
    WAITVM(0);
    SBAR();
  }

  // ---- epilogue: exp-sum over 8 slot-columns per class ----
  const int rbase = n0 + wm * 128 + ((l >> 4) * 4);
  #pragma unroll
  for (int mi = 0; mi < 8; ++mi) {
    #pragma unroll
    for (int ni = 0; ni < 4; ++ni) {
      const int colbase = r0 + wn * 64 + ni * 16 + (l & 15);
      const int cls = colbase >> 3;
      #pragma unroll
      for (int rg = 0; rg < 4; ++rg) {
        float e = __expf(acc[mi][ni][rg] - 1.0f);
        e += __shfl_xor(e, 1);
        e += __shfl_xor(e, 2);
        e += __shfl_xor(e, 4);
        if ((l & 7) == 0 && cls < KK) {
          out[(size_t)(rbase + mi * 16 + rg) * KK + cls] = -fminf(e, 3.0e38f);
        }
      }
    }
  }
}

extern "C" void kernel_launch(void* const* d_in, const int* in_sizes, int n_in,
                              void* d_out, int out_size, void* d_ws, size_t ws_size,
                              hipStream_t stream) {
  const float* x    = (const float*)d_in[0];
  const float* tl   = (const float*)d_in[1];
  const float* mem  = (const float*)d_in[2];
  const float* ment = (const float*)d_in[3];
  float* out = (float*)d_out;

  char* ws = (char*)d_ws;
  int2*     cand = (int2*)ws;                      // 64 KB
  int*      sel  = (int*)(ws + NN * 8);            // 32 KB
  ushort_t* Bb   = (ushort_t*)(ws + (1 << 20));                        // RRP*DD*2 = 16.78 MB
  ushort_t* xb   = (ushort_t*)(ws + (1 << 20) + (size_t)RRP * DD * 2); // NN*DD*2 = 16.78 MB

  hipLaunchKernelGGL(stats_kernel, dim3(NN), dim3(256), 0, stream, tl, cand);
  hipLaunchKernelGGL(select_kernel, dim3(250), dim3(256), 0, stream, cand, ment, sel);
  hipLaunchKernelGGL(convgather_kernel, dim3(NN + RRP), dim3(128), 0, stream,
                     x, mem, sel, xb, Bb);
  hipLaunchKernelGGL(logits_kernel, dim3(32, 32), dim3(512), 0, stream, xb, Bb, out);
}

// Round 10
// 235.432 us; speedup vs baseline: 5.9850x; 1.0258x over previous
//
#include <hip/hip_runtime.h>
#include <hip/hip_bf16.h>
#include <math.h>

#define NN 8192
#define KK 1000
#define SS 8
#define DD 1024
#define RR (KK * SS)   // 8000 memory rows
#define RRP 8192       // padded to 32 * 256

typedef __bf16 bf16x8 __attribute__((ext_vector_type(8)));
typedef float f32x4 __attribute__((ext_vector_type(4)));
typedef unsigned short ushort_t;
typedef ushort_t ushort8 __attribute__((ext_vector_type(8)));

static __device__ __forceinline__ ushort_t f2bf(float f) {
  unsigned u = __float_as_uint(f);
  unsigned r = (u + 0x7FFFu + ((u >> 16) & 1u)) >> 16;  // round-nearest-even
  return (ushort_t)r;
}

// direct global->LDS DMA, 16 B per lane; LDS dest = wave-uniform base + lane*16
#define GLD16(gsrc, ldst)                                                     \
  __builtin_amdgcn_global_load_lds(                                           \
      (const __attribute__((address_space(1))) unsigned int*)(gsrc),          \
      (__attribute__((address_space(3))) unsigned int*)(ldst), 16, 0, 0)

#define SBAR() asm volatile("s_barrier" ::: "memory")
#define WAITVM(n) asm volatile("s_waitcnt vmcnt(" #n ")" ::: "memory")

// ---------------------------------------------------------------------------
// Kernel A: per-sample softmax stats -> packed candidate record.
// ---------------------------------------------------------------------------
__global__ __launch_bounds__(256) void stats_kernel(
    const float* __restrict__ tl, int2* __restrict__ cand) {
  __shared__ float sv[KK];
  __shared__ float redv[256];
  __shared__ int   redi[256];
  const int n = blockIdx.x;
  const int t = threadIdx.x;
  const float* row = tl + (size_t)n * KK;
  for (int j = t; j < KK; j += 256) sv[j] = row[j];
  __syncthreads();

  float bv = -INFINITY; int bi = KK;
  for (int j = t; j < KK; j += 256) { float v = sv[j]; if (v > bv) { bv = v; bi = j; } }
  redv[t] = bv; redi[t] = bi;
  __syncthreads();
  for (int off = 128; off > 0; off >>= 1) {
    if (t < off) {
      float ov = redv[t + off]; int oi = redi[t + off];
      if (ov > redv[t] || (ov == redv[t] && oi < redi[t])) { redv[t] = ov; redi[t] = oi; }
    }
    __syncthreads();
  }
  const float m = redv[0];
  const int lab = redi[0];
  __syncthreads();

  float z = 0.f;
  for (int j = t; j < KK; j += 256) z += expf(sv[j] - m);
  redv[t] = z;
  __syncthreads();
  for (int off = 128; off > 0; off >>= 1) {
    if (t < off) redv[t] += redv[t + off];
    __syncthreads();
  }
  const float Z = redv[0];
  __syncthreads();

  float h = 0.f;
  for (int j = t; j < KK; j += 256) {
    float p = expf(sv[j] - m) / Z;
    h -= p * logf(p + 1e-6f);
  }
  redv[t] = h;
  __syncthreads();
  for (int off = 128; off > 0; off >>= 1) {
    if (t < off) redv[t] += redv[t + off];
    __syncthreads();
  }
  if (t == 0) {
    const float H = redv[0];
    const float plab = 1.0f / Z;
    const bool c = (plab > 0.03f) && (H > 0.2f) && (H < 0.5f);
    cand[n] = make_int2(c ? lab : -1, __float_as_int(H));
  }
}

// ---------------------------------------------------------------------------
// Kernel B: per-class sequential eviction, wave-parallel scan.
// ---------------------------------------------------------------------------
__global__ __launch_bounds__(256) void select_kernel(
    const int2* __restrict__ cand, const float* __restrict__ ment,
    int* __restrict__ sel) {
  const int w = threadIdx.x >> 6;
  const int l = threadIdx.x & 63;
  const int k = blockIdx.x * 4 + w;
  if (k >= KK) return;

  float ent[SS]; int idx[SS];
  #pragma unroll
  for (int s = 0; s < SS; ++s) { ent[s] = ment[k * SS + s]; idx[s] = -1; }

  for (int base = 0; base < NN; base += 64) {
    const int2 c = cand[base + l];
    unsigned long long msk = __ballot(c.x == k);
    while (msk) {
      const int src = __ffsll((long long)msk) - 1;
      msk &= msk - 1;
      const float H = __shfl(__int_as_float(c.y), src);
      float mx = ent[0]; int mi = 0;
      #pragma unroll
      for (int s = 1; s < SS; ++s) if (ent[s] > mx) { mx = ent[s]; mi = s; }
      if (H < mx) { ent[mi] = H; idx[mi] = base + src; }
    }
  }
  if (l == 0) {
    #pragma unroll
    for (int s = 0; s < SS; ++s) sel[k * SS + s] = idx[s];
  }
}

// ---------------------------------------------------------------------------
// Kernel B2: fused convert+gather.
// r < NN:  xb[r]  = bf16(x[r])
// r >= NN: Bb[r-NN] = bf16(final memory row r-NN)  (sel>=0 -> x row, pad->0)
// ---------------------------------------------------------------------------
__global__ __launch_bounds__(128) void convgather_kernel(
    const float* __restrict__ x, const float* __restrict__ mem,
    const int* __restrict__ sel, ushort_t* __restrict__ xb,
    ushort_t* __restrict__ Bb) {
  const int r = blockIdx.x;
  const int t = threadIdx.x;
  const float* src;
  ushort_t* dst;
  if (r < NN) {
    src = x + (size_t)r * DD;
    dst = xb + (size_t)r * DD;
  } else {
    const int rr = r - NN;
    dst = Bb + (size_t)rr * DD;
    if (rr >= RR) {
      *(ushort8*)(dst + t * 8) = (ushort8)0;
      return;
    }
    const int sl = sel[rr];
    src = (sl >= 0) ? (x + (size_t)sl * DD) : (mem + (size_t)rr * DD);
  }
  const float4 a = *(const float4*)(src + t * 8);
  const float4 b = *(const float4*)(src + t * 8 + 4);
  ushort8 o;
  o[0] = f2bf(a.x); o[1] = f2bf(a.y); o[2] = f2bf(a.z); o[3] = f2bf(a.w);
  o[4] = f2bf(b.x); o[5] = f2bf(b.y); o[6] = f2bf(b.z); o[7] = f2bf(b.w);
  *(ushort8*)(dst + t * 8) = o;
}

// ---------------------------------------------------------------------------
// Kernel C: bf16 MFMA GEMM + exp-sum epilogue — 8-phase (m201-style) port.
// BM=BN=256, BK=64, 8 waves (2M x 4N), 512 threads. 2 LDS buffers of one
// K-step each (A[256][64] + B[256][64] bf16 = 64 KB; total 128 KB).
// Per K-step: 4 phases x {ds_read subtile || 2xGLD16 stage || SBAR ||
// setprio(1) 16 MFMA setprio(0) || SBAR}. Counted vmcnt, never 0 mid-loop.
//
// Chunk map (8KB chunks = 64 rows): A-c0..3 = rows 0-63..192-255; B likewise.
// Wave (wm,wn) reads: ph0: B-chunk wn (held in regs all step) + A-chunk 2wm;
// ph1: A-chunk 2wm; ph2-3: A-chunk 2wm+1.
// Stage order for step T+1 during step T (2 GLD16/thread/phase):
//   ph0:(A-c0,A-c2) ph1:(B-c0,B-c2) ph2:(B-c1,B-c3) ph3:(A-c1,A-c3)
// Per-wave FIFO ledger (2 issues/phase):
//   boundary wait vmcnt(2): leaves only (A-c1,A-c3) of T+1 in flight; all of
//     ph0/ph1 needs (pairs 0,1,2) landed. Slack >= 2 phases.
//   ph2 wait vmcnt(4): outstanding = [pair3 of T(2)] + [pairs0,1 of T+1(4)];
//     drains pair3 = exactly the A-chunk ph2/ph3 read. Slack 3 phases.
//   Tail: T=NT-1 stages nothing -> ph2 wait becomes vmcnt(0).
// WAR: stages target buffer (T+1)&1, reads target T&1 — disjoint always.
// Swizzle (128B rows, 8 chunks): slot c^(row&7) holds global chunk c; staged
// by permuting per-lane global source (rule #21), read with same XOR ->
// <=2-way bank aliasing (free). MFMA clusters pinned with sched_barrier(0).
// ---------------------------------------------------------------------------
#define BKS 64
#define NTS (DD / BKS)   // 16 K-steps
#define LDSH 32768       // ushorts per buffer (A 16384 + B 16384)

__global__ __launch_bounds__(512, 2) void logits_kernel(
    const ushort_t* __restrict__ xb, const ushort_t* __restrict__ Bb,
    float* __restrict__ out) {
  __shared__ ushort_t lds[2 * LDSH];  // 128 KB
  const int t = threadIdx.x;
  const int w = t >> 6;    // wave 0..7
  const int l = t & 63;
  const int wm = w >> 2;   // 0..1: M-half (128 rows)
  const int wn = w & 3;    // 0..3: N-quarter (64 cols)
  const int n0 = blockIdx.x * 256;
  const int r0 = blockIdx.y * 256;

  // ---- staging constants: one GLD16 = 8 rows (64 lanes x 16B, 128B rows)
  // lane covers row chunkbase + w*8 + (l>>3), LDS slot sc = l&7,
  // global chunk = sc ^ (ldsrow&7) = (l&7) ^ ((l>>3)&7)
  const int srow = w * 8 + (l >> 3);
  const int gcolh = (((l & 7) ^ ((l >> 3) & 7)) << 3);  // halves
  const ushort_t* gA = xb + (size_t)(n0 + srow) * DD + gcolh;
  const ushort_t* gB = Bb + (size_t)(r0 + srow) * DD + gcolh;

#define STAGE_AC(T, c)                                                        \
  GLD16(gA + (size_t)(c) * 64 * DD + (size_t)(T) * BKS,                       \
        lds + ((T) & 1) * LDSH + (c) * 4096 + w * 512)
#define STAGE_BC(T, c)                                                        \
  GLD16(gB + (size_t)(c) * 64 * DD + (size_t)(T) * BKS,                       \
        lds + ((T) & 1) * LDSH + 16384 + (c) * 4096 + w * 512)

  // ---- read-side constants (ushort units) ----
  const int lr = l & 15;
  const int ch = l >> 4;  // 16B k-chunk within kk-slice, 0..3
  const int kc0 = ((ch ^ (lr & 7)) << 3);        // kk=0: chunk ch
  const int kc1 = (((4 + ch) ^ (lr & 7)) << 3);  // kk=1: chunk 4+ch
  const int arow = (wm * 128 + lr) * 64;         // + mi*1024
  const int brow = 16384 + (wn * 64 + lr) * 64;  // + ni*1024

  f32x4 acc[8][4];
  #pragma unroll
  for (int mi = 0; mi < 8; ++mi)
    #pragma unroll
    for (int ni = 0; ni < 4; ++ni) acc[mi][ni] = (f32x4){0.f, 0.f, 0.f, 0.f};

  // ---- prologue: stage step 0 in pair order, leave pair3 in flight ----
  STAGE_AC(0, 0); STAGE_AC(0, 2);
  STAGE_BC(0, 0); STAGE_BC(0, 2);
  STAGE_BC(0, 1); STAGE_BC(0, 3);
  STAGE_AC(0, 1); STAGE_AC(0, 3);
  WAITVM(2);
  SBAR();

#define MFMA_CLUSTER(q)                                                       \
  do {                                                                        \
    __builtin_amdgcn_sched_barrier(0);                                        \
    __builtin_amdgcn_s_setprio(1);                                            \
    _Pragma("unroll")                                                         \
    for (int i = 0; i < 2; ++i)                                               \
      _Pragma("unroll")                                                       \
      for (int ni = 0; ni < 4; ++ni)                                          \
        acc[2 * (q) + i][ni] = __builtin_amdgcn_mfma_f32_16x16x32_bf16(       \
            af[i][0], bf[ni][0], acc[2 * (q) + i][ni], 0, 0, 0);              \
    _Pragma("unroll")                                                         \
    for (int i = 0; i < 2; ++i)                                               \
      _Pragma("unroll")                                                       \
      for (int ni = 0; ni < 4; ++ni)                                          \
        acc[2 * (q) + i][ni] = __builtin_amdgcn_mfma_f32_16x16x32_bf16(       \
            af[i][1], bf[ni][1], acc[2 * (q) + i][ni], 0, 0, 0);              \
    __builtin_amdgcn_s_setprio(0);                                            \
    __builtin_amdgcn_sched_barrier(0);                                        \
  } while (0)

  #pragma unroll 2
  for (int T = 0; T < NTS; ++T) {
    const ushort_t* buf = lds + (T & 1) * LDSH;
    const int Tn = T + 1;
    const bool st = (Tn < NTS);
    bf16x8 bf[4][2];
    bf16x8 af[2][2];

    // ---- phase 0: B all (regs for whole step) + A mi0,1; stage (A-c0,A-c2)
    #pragma unroll
    for (int ni = 0; ni < 4; ++ni) {
      bf[ni][0] = *(const bf16x8*)(buf + brow + ni * 1024 + kc0);
      bf[ni][1] = *(const bf16x8*)(buf + brow + ni * 1024 + kc1);
    }
    af[0][0] = *(const bf16x8*)(buf + arow + kc0);
    af[0][1] = *(const bf16x8*)(buf + arow + kc1);
    af[1][0] = *(const bf16x8*)(buf + arow + 1024 + kc0);
    af[1][1] = *(const bf16x8*)(buf + arow + 1024 + kc1);
    if (st) { STAGE_AC(Tn, 0); STAGE_AC(Tn, 2); }
    SBAR();
    MFMA_CLUSTER(0);
    SBAR();

    // ---- phase 1: A mi2,3; stage (B-c0,B-c2)
    af[0][0] = *(const bf16x8*)(buf + arow + 2048 + kc0);
    af[0][1] = *(const bf16x8*)(buf + arow + 2048 + kc1);
    af[1][0] = *(const bf16x8*)(buf + arow + 3072 + kc0);
    af[1][1] = *(const bf16x8*)(buf + arow + 3072 + kc1);
    if (st) { STAGE_BC(Tn, 0); STAGE_BC(Tn, 2); }
    SBAR();
    MFMA_CLUSTER(1);
    SBAR();

    // ---- phase 2: drain this step's late A-halves, A mi4,5; stage (B-c1,B-c3)
    if (T < NTS - 1) { WAITVM(4); } else { WAITVM(0); }
    af[0][0] = *(const bf16x8*)(buf + arow + 4096 + kc0);
    af[0][1] = *(const bf16x8*)(buf + arow + 4096 + kc1);
    af[1][0] = *(const bf16x8*)(buf + arow + 5120 + kc0);
    af[1][1] = *(const bf16x8*)(buf + arow + 5120 + kc1);
    if (st) { STAGE_BC(Tn, 1); STAGE_BC(Tn, 3); }
    SBAR();
    MFMA_CLUSTER(2);
    SBAR();

    // ---- phase 3: A mi6,7; stage (A-c1,A-c3); boundary wait vmcnt(2)
    af[0][0] = *(const bf16x8*)(buf + arow + 6144 + kc0);
    af[0][1] = *(const bf16x8*)(buf + arow + 6144 + kc1);
    af[1][0] = *(const bf16x8*)(buf + arow + 7168 + kc0);
    af[1][1] = *(const bf16x8*)(buf + arow + 7168 + kc1);
    if (st) { STAGE_AC(Tn, 1); STAGE_AC(Tn, 3); }
    SBAR();
    MFMA_CLUSTER(3);
    WAITVM(2);  // pairs 0,1,2 of step T+1 landed; pair3 may fly
    SBAR();
  }

  // ---- epilogue: exp-sum over 8 slot-columns per class ----
  const int rbase = n0 + wm * 128 + ((l >> 4) * 4);
  #pragma unroll
  for (int mi = 0; mi < 8; ++mi) {
    #pragma unroll
    for (int ni = 0; ni < 4; ++ni) {
      const int colbase = r0 + wn * 64 + ni * 16 + (l & 15);
      const int cls = colbase >> 3;
      #pragma unroll
      for (int rg = 0; rg < 4; ++rg) {
        float e = __expf(acc[mi][ni][rg] - 1.0f);
        e += __shfl_xor(e, 1);
        e += __shfl_xor(e, 2);
        e += __shfl_xor(e, 4);
        if ((l & 7) == 0 && cls < KK) {
          out[(size_t)(rbase + mi * 16 + rg) * KK + cls] = -fminf(e, 3.0e38f);
        }
      }
    }
  }
}

extern "C" void kernel_launch(void* const* d_in, const int* in_sizes, int n_in,
                              void* d_out, int out_size, void* d_ws, size_t ws_size,
                              hipStream_t stream) {
  const float* x    = (const float*)d_in[0];
  const float* tl   = (const float*)d_in[1];
  const float* mem  = (const float*)d_in[2];
  const float* ment = (const float*)d_in[3];
  float* out = (float*)d_out;

  char* ws = (char*)d_ws;
  int2*     cand = (int2*)ws;                      // 64 KB
  int*      sel  = (int*)(ws + NN * 8);            // 32 KB
  ushort_t* Bb   = (ushort_t*)(ws + (1 << 20));                        // RRP*DD*2 = 16.78 MB
  ushort_t* xb   = (ushort_t*)(ws + (1 << 20) + (size_t)RRP * DD * 2); // NN*DD*2 = 16.78 MB

  hipLaunchKernelGGL(stats_kernel, dim3(NN), dim3(256), 0, stream, tl, cand);
  hipLaunchKernelGGL(select_kernel, dim3(250), dim3(256), 0, stream, cand, ment, sel);
  hipLaunchKernelGGL(convgather_kernel, dim3(NN + RRP), dim3(128), 0, stream,
                     x, mem, sel, xb, Bb);
  hipLaunchKernelGGL(logits_kernel, dim3(32, 32), dim3(512), 0, stream, xb, Bb, out);
}